// Round 3
// baseline (23.464 us; speedup 1.0000x reference)
//
#include <hip/hip_runtime.h>

// out[b,o] = min_i max(x[b,i], w[i,o])   (forward value of the STE expression;
// stop_gradient(hard - smooth) + smooth == hard numerically).
// x: [B=4096][K=256] f32, w: [K=256][O=256] f32, out: [B][O] f32.
//
// f16 packed min/max (v_pk_max_f16 / v_pk_min_f16 = 2 ops/instr), packed along
// the reduction dim (i, i+1); accumulator lanes merged at the epilogue.
//
// R3 change vs R2: occupancy 1 -> 4 waves/SIMD. 1024 threads/block, same 64x64
// tile, 4 outputs/thread (4 rows x 1 col). tr = t>>6 is wave-uniform so x LDS
// reads are pure broadcast; w read is ds_read_b64 (volume-optimal). VALU work
// per SIMD unchanged (~8192 cy); ds_read latency now hidden by 4 waves.
//
// LDS (64 KB): xs 32 KB: i-quad blocks of 512 B, 32 lines x 16 B, line L holds
// rows (L, L+32) as {pairA,pairB}; line index XORed with (i4&31) so staging
// writes (lane==i4) hit all 32 banks. ws 32 KB: per i4 512 B = 64 cols x 8 B
// {pairA(i,i+1), pairB(i+2,i+3)}.

typedef _Float16 h2 __attribute__((ext_vector_type(2)));

union U4H { uint4 u; h2 h[4]; };
union U2H { uint2 u; h2 h[2]; };

static __device__ __forceinline__ h2 pmin(h2 a, h2 b) {
#if __has_builtin(__builtin_elementwise_min)
    return __builtin_elementwise_min(a, b);
#else
    h2 d; asm("v_pk_min_f16 %0, %1, %2" : "=v"(d) : "v"(a), "v"(b)); return d;
#endif
}
static __device__ __forceinline__ h2 pmax(h2 a, h2 b) {
#if __has_builtin(__builtin_elementwise_max)
    return __builtin_elementwise_max(a, b);
#else
    h2 d; asm("v_pk_max_f16 %0, %1, %2" : "=v"(d) : "v"(a), "v"(b)); return d;
#endif
}

__global__ __launch_bounds__(1024, 4)
void SmoothSTEMinMax_kernel(const float* __restrict__ x,
                            const float* __restrict__ w,
                            float* __restrict__ out) {
    __shared__ __align__(16) unsigned char smem[65536];
    unsigned char* xs = smem;            // 32 KB
    unsigned char* ws = smem + 32768;    // 32 KB

    const int t  = threadIdx.x;
    const int r0 = blockIdx.y * 64;      // row tile base (batch)
    const int c0 = blockIdx.x * 64;      // col tile base (out_features)

    // ---- stage x: 64 rows x 256 i -> f16 i-quad blocks ----
    // lane: i4 = t&63 (== lane), wv = t>>6 (wave id, 0..15); rr = 16k+wv.
    // Global: float4 = 16 B/lane, 1 KB/wave-instr, fully coalesced.
    // LDS: 16 B write at line (rr ^ (i4&31)) -> all 32 banks, conflict-free.
    {
        const int i4 = t & 63;
        const int wv = t >> 6;
#pragma unroll
        for (int k = 0; k < 2; ++k) {
            const int rr = (k << 4) + wv;                 // 0..31
            const float4 va = *reinterpret_cast<const float4*>(&x[(size_t)(r0 + rr)      * 256 + (i4 << 2)]);
            const float4 vb = *reinterpret_cast<const float4*>(&x[(size_t)(r0 + rr + 32) * 256 + (i4 << 2)]);
            U4H q;
            q.h[0] = h2{(_Float16)va.x, (_Float16)va.y};   // row rr,    pair A
            q.h[1] = h2{(_Float16)va.z, (_Float16)va.w};   // row rr,    pair B
            q.h[2] = h2{(_Float16)vb.x, (_Float16)vb.y};   // row rr+32, pair A
            q.h[3] = h2{(_Float16)vb.z, (_Float16)vb.w};   // row rr+32, pair B
            const int line = rr ^ (i4 & 31);
            *reinterpret_cast<uint4*>(xs + (i4 << 9) + (line << 4)) = q.u;
        }
    }

    // ---- stage w: per i4, 64 cols x 8 B {pairA, pairB} ----
    // flat = 1024k + t: i4 = flat>>6 (wave-uniform), col = lane.
    // 4 scalar f32 loads per unit, each 256 B/wave coalesced.
#pragma unroll
    for (int k = 0; k < 4; ++k) {
        const int flat = (k << 10) + t;
        const int i4  = (flat >> 6) & 63;
        const int col = flat & 63;
        const float f0 = w[(size_t)((i4 << 2) + 0) * 256 + c0 + col];
        const float f1 = w[(size_t)((i4 << 2) + 1) * 256 + c0 + col];
        const float f2 = w[(size_t)((i4 << 2) + 2) * 256 + c0 + col];
        const float f3 = w[(size_t)((i4 << 2) + 3) * 256 + c0 + col];
        U2H q;
        q.h[0] = h2{(_Float16)f0, (_Float16)f1};   // pair A
        q.h[1] = h2{(_Float16)f2, (_Float16)f3};   // pair B
        *reinterpret_cast<uint2*>(ws + (i4 << 9) + (col << 3)) = q.u;
    }

    __syncthreads();

    // ---- compute: 4 outputs/thread (rows {2tr, 2tr+32, 2tr+1, 2tr+33}, col tc)
    const int tr = t >> 6;    // wave-uniform -> x reads are LDS broadcast
    const int tc = t & 63;

    h2 acc0, acc1, acc2, acc3;
    const h2 big = h2{(_Float16)65504.0f, (_Float16)65504.0f};
    acc0 = acc1 = acc2 = acc3 = big;

#pragma unroll 4
    for (int i4 = 0; i4 < 64; ++i4) {
        const unsigned char* xb = xs + (i4 << 9);
        const int kk = i4 & 31;
        U4H xu0, xu1; U2H wq;
        xu0.u = *reinterpret_cast<const uint4*>(xb + ((((tr << 1)    ) ^ kk) << 4)); // rows 2tr, 2tr+32
        xu1.u = *reinterpret_cast<const uint4*>(xb + ((((tr << 1) | 1) ^ kk) << 4)); // rows 2tr+1, 2tr+33
        wq.u  = *reinterpret_cast<const uint2*>(ws + (i4 << 9) + (tc << 3));

        const h2 wA = wq.h[0], wB = wq.h[1];
        acc0 = pmin(acc0, pmax(xu0.h[0], wA)); acc0 = pmin(acc0, pmax(xu0.h[1], wB));
        acc1 = pmin(acc1, pmax(xu0.h[2], wA)); acc1 = pmin(acc1, pmax(xu0.h[3], wB));
        acc2 = pmin(acc2, pmax(xu1.h[0], wA)); acc2 = pmin(acc2, pmax(xu1.h[1], wB));
        acc3 = pmin(acc3, pmax(xu1.h[2], wA)); acc3 = pmin(acc3, pmax(xu1.h[3], wB));
    }

    // ---- epilogue: merge packed lanes, scalar f32 stores (256 B/wave, coalesced)
    const int rowm[4] = { 2 * tr, 2 * tr + 32, 2 * tr + 1, 2 * tr + 33 };
    const float o0 = fminf((float)acc0.x, (float)acc0.y);
    const float o1 = fminf((float)acc1.x, (float)acc1.y);
    const float o2 = fminf((float)acc2.x, (float)acc2.y);
    const float o3 = fminf((float)acc3.x, (float)acc3.y);
    out[(size_t)(r0 + rowm[0]) * 256 + c0 + tc] = o0;
    out[(size_t)(r0 + rowm[1]) * 256 + c0 + tc] = o1;
    out[(size_t)(r0 + rowm[2]) * 256 + c0 + tc] = o2;
    out[(size_t)(r0 + rowm[3]) * 256 + c0 + tc] = o3;
}

extern "C" void kernel_launch(void* const* d_in, const int* in_sizes, int n_in,
                              void* d_out, int out_size, void* d_ws, size_t ws_size,
                              hipStream_t stream) {
    const float* x = (const float*)d_in[0];
    const float* w = (const float*)d_in[1];
    float* out = (float*)d_out;

    const int batch = in_sizes[0] / 256;   // 4096
    dim3 grid(256 / 64, batch / 64);       // (4, 64) = 256 blocks
    dim3 block(1024);
    hipLaunchKernelGGL(SmoothSTEMinMax_kernel, grid, block, 0, stream, x, w, out);
}